// Round 11
// baseline (286.156 us; speedup 1.0000x reference)
//
#include <hip/hip_runtime.h>

typedef unsigned short u16;
typedef short vshort8 __attribute__((ext_vector_type(8)));
typedef __bf16 vbf16x8 __attribute__((ext_vector_type(8)));
typedef float vf32x4 __attribute__((ext_vector_type(4)));
typedef float vf32x16 __attribute__((ext_vector_type(16)));

__device__ __forceinline__ u16 f2bf(float f) {
  unsigned u = __builtin_bit_cast(unsigned, f);
  u += 0x7FFFu + ((u >> 16) & 1u);
  return (u16)(u >> 16);
}

__device__ __forceinline__ unsigned cvtpk(float lo, float hi) {
  unsigned r;
  asm("v_cvt_pk_bf16_f32 %0, %1, %2" : "=v"(r) : "v"(lo), "v"(hi));
  return r;
}

// v_permlane32_swap_b32 a,b: a' = {a.lo32lanes, b.lo32lanes}, b' = {a.hi32lanes, b.hi32lanes}
__device__ __forceinline__ void plswap(unsigned& a, unsigned& b) {
  asm("v_permlane32_swap_b32 %0, %1" : "+v"(a), "+v"(b));
}

// y[lane] = x[lane^32]
__device__ __forceinline__ float swap32f(float x) { return __shfl_xor(x, 32); }

__device__ __forceinline__ vf32x4 mfma_bf16(vshort8 a, vshort8 b, vf32x4 c) {
  return __builtin_amdgcn_mfma_f32_16x16x32_bf16(
      __builtin_bit_cast(vbf16x8, a), __builtin_bit_cast(vbf16x8, b), c, 0, 0, 0);
}

__device__ __forceinline__ vf32x16 mfma32(vshort8 a, vshort8 b, vf32x16 c) {
  return __builtin_amdgcn_mfma_f32_32x32x16_bf16(
      __builtin_bit_cast(vbf16x8, a), __builtin_bit_cast(vbf16x8, b), c, 0, 0, 0);
}

__device__ __forceinline__ void gload16(const void* g, void* l) {
  __builtin_amdgcn_global_load_lds(
      (const __attribute__((address_space(1))) void*)g,
      (__attribute__((address_space(3))) void*)l, 16, 0, 0);
}

// ---------------- weight transpose + cvt: W[k][n] f32 -> Wt[n][k] bf16 (4 via z) ----------------
__global__ __launch_bounds__(256) void wtrans4(const float* __restrict__ w0,
                                               const float* __restrict__ w1,
                                               const float* __restrict__ w2,
                                               const float* __restrict__ w3,
                                               u16* __restrict__ o0, u16* __restrict__ o1,
                                               u16* __restrict__ o2, u16* __restrict__ o3) {
  int z = blockIdx.z;
  const float* W = z == 0 ? w0 : z == 1 ? w1 : z == 2 ? w2 : w3;
  u16* Wt = z == 0 ? o0 : z == 1 ? o1 : z == 2 ? o2 : o3;
  __shared__ u16 tile[64][72];
  int t = threadIdx.x;
  int n0 = blockIdx.x * 64, k0 = blockIdx.y * 64;
#pragma unroll
  for (int it = 0; it < 4; ++it) {
    int cid = it * 256 + t;
    int r = cid >> 4, c4 = cid & 15;
    float4 v = *(const float4*)&W[(k0 + r) * 1024 + n0 + c4 * 4];
    u16* d = &tile[r][c4 * 4];
    d[0] = f2bf(v.x); d[1] = f2bf(v.y); d[2] = f2bf(v.z); d[3] = f2bf(v.w);
  }
  __syncthreads();
#pragma unroll
  for (int it = 0; it < 4; ++it) {
    int cid = it * 256 + t;
    int rn = cid >> 4, c4 = cid & 15;
    unsigned lo = (unsigned)tile[c4 * 4 + 0][rn] | ((unsigned)tile[c4 * 4 + 1][rn] << 16);
    unsigned hi = (unsigned)tile[c4 * 4 + 2][rn] | ((unsigned)tile[c4 * 4 + 3][rn] << 16);
    uint2 o; o.x = lo; o.y = hi;
    *(uint2*)&Wt[(n0 + rn) * 1024 + k0 + c4 * 4] = o;
  }
}

// ---------------- V transpose: V[b*2048+s][h*64+d] -> Vt[(bh*64+d)][s] (bf16) ----------------
__global__ __launch_bounds__(256) void vtrans(const u16* __restrict__ V,
                                              u16* __restrict__ Vt) {
  __shared__ u16 tile[64][72];
  int t = threadIdx.x;
  int s0 = blockIdx.x * 64;
  int bh = blockIdx.y, b = bh >> 4, h = bh & 15;
#pragma unroll
  for (int it = 0; it < 2; ++it) {
    int cid = it * 256 + t;
    int r = cid >> 3, c8 = cid & 7;
    vshort8 v = *(const vshort8*)&V[(size_t)(b * 2048 + s0 + r) * 1024 + h * 64 + c8 * 8];
    *(vshort8*)&tile[r][c8 * 8] = v;
  }
  __syncthreads();
#pragma unroll
  for (int it = 0; it < 2; ++it) {
    int cid = it * 256 + t;
    int rd = cid >> 3, c8 = cid & 7;
    unsigned w[4];
#pragma unroll
    for (int j = 0; j < 4; ++j) {
      unsigned lo = tile[c8 * 8 + 2 * j][rd];
      unsigned hi = tile[c8 * 8 + 2 * j + 1][rd];
      w[j] = lo | (hi << 16);
    }
    uint4 o; o.x = w[0]; o.y = w[1]; o.z = w[2]; o.w = w[3];
    *(uint4*)&Vt[(size_t)(bh * 64 + rd) * 2048 + s0 + c8 * 8] = o;
  }
}

// ---------------- bf16 GEMM core, A staged from fp32 with inline convert ----------------
// A: fp32 [M,K]; Bt: bf16 [N,K]. LDS mapping identical to the gload_lds path:
// linear dest slot (cid) holds data from swizzled source chunk sc = c ^ (row&7).
__device__ __forceinline__ void gemm_core_f32A(const float* __restrict__ A,
                                               const u16* __restrict__ Bt,
                                               u16* __restrict__ Cb,
                                               int M, int N, int K, float oscale) {
  __shared__ __align__(16) u16 As[128 * 64];
  __shared__ __align__(16) u16 Bs[128 * 64];
  int t = threadIdx.x, lane = t & 63, wid = t >> 6;
  int g = lane >> 4, i16 = lane & 15;
  int n0 = blockIdx.x * 128, m0 = blockIdx.y * 128;
  int wm = wid >> 1, wn = wid & 1;

  vf32x4 acc[4][4];
#pragma unroll
  for (int a = 0; a < 4; ++a)
#pragma unroll
    for (int b = 0; b < 4; ++b) acc[a][b] = (vf32x4){0.f, 0.f, 0.f, 0.f};

  int ldsbase = (wid * 64) * 8;
  for (int kt = 0; kt < K / 64; ++kt) {
    if (kt) __syncthreads();
    // A: fp32 load + inline cvt + ds_write (reg-staged; same swizzle mapping)
#pragma unroll
    for (int it = 0; it < 4; ++it) {
      int cid = it * 256 + t;
      int row = cid >> 3, c = cid & 7, sc = c ^ (row & 7);
      const float* src = &A[(size_t)(m0 + row) * K + kt * 64 + sc * 8];
      float4 v0 = *(const float4*)src;
      float4 v1 = *(const float4*)(src + 4);
      uint4 p;
      p.x = cvtpk(v0.x, v0.y); p.y = cvtpk(v0.z, v0.w);
      p.z = cvtpk(v1.x, v1.y); p.w = cvtpk(v1.z, v1.w);
      *(uint4*)&As[cid * 8] = p;
    }
    // B: async global->LDS (bf16)
#pragma unroll
    for (int it = 0; it < 4; ++it) {
      int cid = it * 256 + t;
      int row = cid >> 3, c = cid & 7, sc = c ^ (row & 7);
      gload16(Bt + (size_t)(n0 + row) * K + kt * 64 + sc * 8, &Bs[it * 2048 + ldsbase]);
    }
    __syncthreads();
#pragma unroll
    for (int kc = 0; kc < 2; ++kc) {
      vshort8 af[4], bf[4];
#pragma unroll
      for (int mf = 0; mf < 4; ++mf) {
        int row = wm * 64 + mf * 16 + i16;
        int ch = (kc * 4 + g) ^ (row & 7);
        af[mf] = *(const vshort8*)&As[row * 64 + ch * 8];
      }
#pragma unroll
      for (int nf = 0; nf < 4; ++nf) {
        int row = wn * 64 + nf * 16 + i16;
        int ch = (kc * 4 + g) ^ (row & 7);
        bf[nf] = *(const vshort8*)&Bs[row * 64 + ch * 8];
      }
#pragma unroll
      for (int mf = 0; mf < 4; ++mf)
#pragma unroll
        for (int nf = 0; nf < 4; ++nf)
          acc[mf][nf] = mfma_bf16(af[mf], bf[nf], acc[mf][nf]);
    }
  }
#pragma unroll
  for (int mf = 0; mf < 4; ++mf)
#pragma unroll
    for (int nf = 0; nf < 4; ++nf)
#pragma unroll
      for (int r = 0; r < 4; ++r) {
        int m = m0 + wm * 64 + mf * 16 + g * 4 + r;
        int n = n0 + wn * 64 + nf * 16 + i16;
        Cb[(size_t)m * N + n] = f2bf(acc[mf][nf][r] * oscale);
      }
}

// all three projections in one launch (z selects input/weight/output)
__global__ __launch_bounds__(256) void gemm_qkv(const float* __restrict__ q,
                                                const float* __restrict__ k,
                                                const float* __restrict__ v,
                                                const u16* __restrict__ wqt,
                                                const u16* __restrict__ wkt,
                                                const u16* __restrict__ wvt,
                                                u16* __restrict__ Qb, u16* __restrict__ Kb,
                                                u16* __restrict__ Vb, float qs) {
  int z = blockIdx.z;
  const float* A = z == 0 ? q : z == 1 ? k : v;
  const u16* B = z == 0 ? wqt : z == 1 ? wkt : wvt;
  u16* C = z == 0 ? Qb : z == 1 ? Kb : Vb;
  gemm_core_f32A(A, B, C, 8192, 1024, 1024, z == 0 ? qs : 1.0f);
}

// ---------------- bf16 GEMM (A bf16 via gload_lds), fp32 out — for the W_O projection ----------------
__global__ __launch_bounds__(256) void gemm_wo(const u16* __restrict__ A,
                                               const u16* __restrict__ Bt,
                                               float* __restrict__ Cf,
                                               int M, int N, int K) {
  __shared__ __align__(16) u16 As[128 * 64];
  __shared__ __align__(16) u16 Bs[128 * 64];
  int t = threadIdx.x, lane = t & 63, wid = t >> 6;
  int g = lane >> 4, i16 = lane & 15;
  int n0 = blockIdx.x * 128, m0 = blockIdx.y * 128;
  int wm = wid >> 1, wn = wid & 1;

  vf32x4 acc[4][4];
#pragma unroll
  for (int a = 0; a < 4; ++a)
#pragma unroll
    for (int b = 0; b < 4; ++b) acc[a][b] = (vf32x4){0.f, 0.f, 0.f, 0.f};

  int ldsbase = (wid * 64) * 8;
  for (int kt = 0; kt < K / 64; ++kt) {
    if (kt) __syncthreads();
#pragma unroll
    for (int it = 0; it < 4; ++it) {
      int cid = it * 256 + t;
      int row = cid >> 3, c = cid & 7, sc = c ^ (row & 7);
      gload16(A + (size_t)(m0 + row) * K + kt * 64 + sc * 8, &As[it * 2048 + ldsbase]);
    }
#pragma unroll
    for (int it = 0; it < 4; ++it) {
      int cid = it * 256 + t;
      int row = cid >> 3, c = cid & 7, sc = c ^ (row & 7);
      gload16(Bt + (size_t)(n0 + row) * K + kt * 64 + sc * 8, &Bs[it * 2048 + ldsbase]);
    }
    __syncthreads();
#pragma unroll
    for (int kc = 0; kc < 2; ++kc) {
      vshort8 af[4], bf[4];
#pragma unroll
      for (int mf = 0; mf < 4; ++mf) {
        int row = wm * 64 + mf * 16 + i16;
        int ch = (kc * 4 + g) ^ (row & 7);
        af[mf] = *(const vshort8*)&As[row * 64 + ch * 8];
      }
#pragma unroll
      for (int nf = 0; nf < 4; ++nf) {
        int row = wn * 64 + nf * 16 + i16;
        int ch = (kc * 4 + g) ^ (row & 7);
        bf[nf] = *(const vshort8*)&Bs[row * 64 + ch * 8];
      }
#pragma unroll
      for (int mf = 0; mf < 4; ++mf)
#pragma unroll
        for (int nf = 0; nf < 4; ++nf)
          acc[mf][nf] = mfma_bf16(af[mf], bf[nf], acc[mf][nf]);
    }
  }
#pragma unroll
  for (int mf = 0; mf < 4; ++mf)
#pragma unroll
    for (int nf = 0; nf < 4; ++nf)
#pragma unroll
      for (int r = 0; r < 4; ++r) {
        int m = m0 + wm * 64 + mf * 16 + g * 4 + r;
        int n = n0 + wn * 64 + nf * 16 + i16;
        Cf[(size_t)m * N + n] = acc[mf][nf][r];
      }
}

// ---------------- fused flash attention: 64 q-rows/wave, zero LDS, K double-buffered ----------------
// (byte-identical to the proven 143.5us attn_fwd9)
__device__ __forceinline__ void attn_body(int kt, const u16* __restrict__ Kbase,
                                          const u16* __restrict__ Vbase,
                                          vshort8 (&kfc)[2][4], vshort8 (&kfn)[2][4],
                                          vshort8 (&qf)[2][4], vf32x16 (&oacc)[2][2],
                                          float (&mrun)[2], float (&lrun)[2],
                                          int l31, int hi) {
  int ktn = kt + 1 < 32 ? kt + 1 : 31;
#pragma unroll
  for (int ks = 0; ks < 2; ++ks)
#pragma unroll
    for (int dc = 0; dc < 4; ++dc)
      kfn[ks][dc] = *(const vshort8*)&Kbase[(size_t)(ktn * 64 + ks * 32 + l31) * 1024 + dc * 16 + hi * 8];

  unsigned pk[2][2][8];
#pragma unroll
  for (int fq = 0; fq < 2; ++fq) {
    vf32x16 sacc[2];
#pragma unroll
    for (int ks = 0; ks < 2; ++ks)
#pragma unroll
      for (int r = 0; r < 16; ++r) sacc[ks][r] = 0.f;
    __builtin_amdgcn_s_setprio(1);
#pragma unroll
    for (int dc = 0; dc < 4; ++dc)
#pragma unroll
      for (int ks = 0; ks < 2; ++ks)
        sacc[ks] = mfma32(kfc[ks][dc], qf[fq][dc], sacc[ks]);
    __builtin_amdgcn_s_setprio(0);

    float tm[8];
#pragma unroll
    for (int r = 0; r < 8; ++r)
      tm[r] = fmaxf(fmaxf(sacc[0][r], sacc[0][r + 8]), fmaxf(sacc[1][r], sacc[1][r + 8]));
#pragma unroll
    for (int r = 0; r < 4; ++r) tm[r] = fmaxf(tm[r], tm[r + 4]);
    float pmax = fmaxf(fmaxf(tm[0], tm[1]), fmaxf(tm[2], tm[3]));
    pmax = fmaxf(pmax, swap32f(pmax));

    if (pmax > mrun[fq] + 8.f) {
      float al = exp2f(mrun[fq] - pmax);
      lrun[fq] *= al;
#pragma unroll
      for (int dm = 0; dm < 2; ++dm)
#pragma unroll
        for (int r = 0; r < 16; ++r) oacc[dm][fq][r] *= al;
      mrun[fq] = pmax;
    }
    float mm = mrun[fq];

    float s0 = 0.f, s1 = 0.f, s2 = 0.f, s3 = 0.f;
#pragma unroll
    for (int ks = 0; ks < 2; ++ks)
#pragma unroll
      for (int u = 0; u < 8; ++u) {
        float p0 = exp2f(sacc[ks][2 * u] - mm);
        float p1 = exp2f(sacc[ks][2 * u + 1] - mm);
        pk[fq][ks][u] = cvtpk(p0, p1);
        if (u & 1) { s0 += p0; s1 += p1; } else { s2 += p0; s3 += p1; }
      }
    lrun[fq] += (s0 + s1) + (s2 + s3);
  }

  vshort8 vtf[2][4];
#pragma unroll
  for (int dm = 0; dm < 2; ++dm)
#pragma unroll
    for (int s = 0; s < 4; ++s)
      vtf[dm][s] = *(const vshort8*)&Vbase[(size_t)(dm * 32 + l31) * 2048 + kt * 64 + s * 16 + hi * 8];

#pragma unroll
  for (int s = 0; s < 4; ++s) {
    vshort8 pb[2];
    const int ks = s >> 1, s1b = s & 1;
#pragma unroll
    for (int fq = 0; fq < 2; ++fq) {
      unsigned x0 = pk[fq][ks][4 * s1b + 0], x1 = pk[fq][ks][4 * s1b + 1];
      unsigned y0 = pk[fq][ks][4 * s1b + 2], y1 = pk[fq][ks][4 * s1b + 3];
      plswap(x0, y0);
      plswap(x1, y1);
      uint4 wv; wv.x = x0; wv.y = x1; wv.z = y0; wv.w = y1;
      pb[fq] = __builtin_bit_cast(vshort8, wv);
    }
    __builtin_amdgcn_s_setprio(1);
#pragma unroll
    for (int dm = 0; dm < 2; ++dm)
#pragma unroll
      for (int fq = 0; fq < 2; ++fq)
        oacc[dm][fq] = mfma32(vtf[dm][s], pb[fq], oacc[dm][fq]);
    __builtin_amdgcn_s_setprio(0);
  }
}

__global__ __launch_bounds__(512, 2) void attn_fwd9(const u16* __restrict__ Q,
                                                    const u16* __restrict__ K,
                                                    const u16* __restrict__ Vt,
                                                    u16* __restrict__ O) {
  int t = threadIdx.x, lane = t & 63, w = t >> 6;
  int l31 = lane & 31, hi = lane >> 5;
  int i = blockIdx.x;                    // 256 blocks
  int qb = (i >> 3) & 3;
  int bh = (i & 7) + 8 * (i >> 5);       // same-bh blocks share XCD
  int b = bh >> 4, h = bh & 15;

  const u16* Qbase = Q + (size_t)(b * 2048 + qb * 512 + w * 64) * 1024 + h * 64;
  const u16* Kbase = K + (size_t)(b * 2048) * 1024 + h * 64;
  const u16* Vbase = Vt + (size_t)(bh * 64) * 2048;

  vshort8 qf[2][4];
#pragma unroll
  for (int fq = 0; fq < 2; ++fq)
#pragma unroll
    for (int dc = 0; dc < 4; ++dc)
      qf[fq][dc] = *(const vshort8*)&Qbase[(size_t)(fq * 32 + l31) * 1024 + dc * 16 + hi * 8];

  vf32x16 oacc[2][2];
#pragma unroll
  for (int dm = 0; dm < 2; ++dm)
#pragma unroll
    for (int fq = 0; fq < 2; ++fq)
#pragma unroll
      for (int r = 0; r < 16; ++r) oacc[dm][fq][r] = 0.f;
  float mrun[2] = {-3.0e38f, -3.0e38f}, lrun[2] = {0.f, 0.f};

  vshort8 kfA[2][4], kfB[2][4];
#pragma unroll
  for (int ks = 0; ks < 2; ++ks)
#pragma unroll
    for (int dc = 0; dc < 4; ++dc)
      kfA[ks][dc] = *(const vshort8*)&Kbase[(size_t)(ks * 32 + l31) * 1024 + dc * 16 + hi * 8];

  for (int kt = 0; kt < 32; kt += 2) {
    attn_body(kt,     Kbase, Vbase, kfA, kfB, qf, oacc, mrun, lrun, l31, hi);
    attn_body(kt + 1, Kbase, Vbase, kfB, kfA, qf, oacc, mrun, lrun, l31, hi);
  }

#pragma unroll
  for (int fq = 0; fq < 2; ++fq) {
    float lt = lrun[fq] + swap32f(lrun[fq]);
    float inv = 1.f / lt;
    size_t qrow = (size_t)(b * 2048 + qb * 512 + w * 64 + fq * 32 + l31);
#pragma unroll
    for (int dm = 0; dm < 2; ++dm)
#pragma unroll
      for (int u = 0; u < 4; ++u) {
        unsigned w0 = cvtpk(oacc[dm][fq][4 * u + 0] * inv, oacc[dm][fq][4 * u + 1] * inv);
        unsigned w1 = cvtpk(oacc[dm][fq][4 * u + 2] * inv, oacc[dm][fq][4 * u + 3] * inv);
        uint2 o; o.x = w0; o.y = w1;
        *(uint2*)&O[qrow * 1024 + h * 64 + dm * 32 + 8 * u + 4 * hi] = o;
      }
  }
}

extern "C" void kernel_launch(void* const* d_in, const int* in_sizes, int n_in,
                              void* d_out, int out_size, void* d_ws, size_t ws_size,
                              hipStream_t stream) {
  const float* q  = (const float*)d_in[0];
  const float* k  = (const float*)d_in[1];
  const float* v  = (const float*)d_in[2];
  const float* wq = (const float*)d_in[3];
  const float* wk = (const float*)d_in[4];
  const float* wv = (const float*)d_in[5];
  const float* wo = (const float*)d_in[6];
  float* out = (float*)d_out;

  const int M = 8192, D = 1024;
  u16* Qb = (u16*)d_out;                // Q,K (bf16) parked in d_out (32MB)
  u16* Kb = Qb + (size_t)M * D;
  u16* xb  = (u16*)d_ws;                // attn-out
  u16* Vb  = xb + (size_t)M * D;
  u16* Vtg = Vb + (size_t)M * D;
  u16* wqt = Vtg + (size_t)M * D;
  u16* wkt = wqt + (size_t)D * D;
  u16* wvt = wkt + (size_t)D * D;
  u16* wot = wvt + (size_t)D * D;

  dim3 blk(256);
  wtrans4<<<dim3(16, 16, 4), blk, 0, stream>>>(wq, wk, wv, wo, wqt, wkt, wvt, wot);

  const float QSCALE = 0.125f * 1.44269504088896f;  // 1/sqrt(64) * log2(e)
  gemm_qkv<<<dim3(8, 64, 3), blk, 0, stream>>>(q, k, v, wqt, wkt, wvt, Qb, Kb, Vb, QSCALE);

  vtrans<<<dim3(32, 64), blk, 0, stream>>>(Vb, Vtg);
  attn_fwd9<<<dim3(256), dim3(512), 0, stream>>>(Qb, Kb, Vtg, xb /* -> attn out */);
  gemm_wo<<<dim3(8, 64), blk, 0, stream>>>(xb, wot, out, M, D, D);
}